// Round 14
// baseline (48.435 us; speedup 1.0000x reference)
//
#include <hip/hip_runtime.h>

#define BB 4
#define RR 160
#define HH 128
#define WW 128
#define CC 64
#define NREG 32
#define PH 7
#define PW 7
#define NTHR 448
#define IOU_THRF 0.4f

// floor division (Python // semantics) for possibly-negative numerators
__device__ __forceinline__ int fdiv(int a, int b) {
    int q = a / b, r = a % b;
    return (r != 0 && ((r < 0) != (b < 0))) ? q - 1 : q;
}

__device__ __forceinline__ void fix_span(int& lo, int& hi, int p, int s) {
    int pad = p - (hi - lo);
    bool fmin = lo < fdiv(pad, 2);
    bool fmax = (s - hi) < fdiv(1 + pad, 2);
    bool sym = (pad > 0) && !(fmin || fmax);
    int lo2 = sym ? lo - fdiv(pad, 2) : lo;
    int hi2 = sym ? hi + fdiv(1 + pad, 2) : hi;
    if ((pad > 0) && fmin) { lo2 = 0; hi2 = p; }
    if ((pad > 0) && fmax) { lo2 = s - p; hi2 = s; }
    lo = lo2; hi = hi2;
}

// Single dispatch, 896 blocks x 448 thr, NO inter-block communication.
// Each block redundantly computes its batch's NMS: register-hoisted 7-wave
// ballot build (~0.7us, parallel across waves), then scan+select+clip on
// WAVE 0 ONLY (serial chain paid once per block, NOT per wave -- R6's LDS
// storm came from 8 waves each broadcasting 480 ds_reads), box broadcast via
// LDS. Pool phase is R5-verbatim: wave = pool-col, lane = (pixel-group,
// channel-quad), float4 coalesced, shfl_xor reduce.
__global__ __launch_bounds__(NTHR)
void fused_nosync(const float* __restrict__ feat, const float* __restrict__ roi,
                  float* __restrict__ out) {
    // R5 pool decode: xcd slot x owns (b,n) pairs [x*16, x*16+16)
    const int g = blockIdx.x;
    const int x = g & 7;
    const int q = g >> 3;
    const int pair = x * 16 + q / 7;
    const int i = q % 7;
    const int n = pair & (NREG - 1);
    const int b = pair >> 5;

    const int tid = threadIdx.x;
    const int wid = tid >> 6;
    const int lane = tid & 63;

    __shared__ float sx[RR], sy[RR], sx1[RR], sy1[RR], sarea[RR];
    __shared__ unsigned long long nsup[RR][3];
    __shared__ int sbox[4];

    // ---- load boxes for batch b ----
    const float* rb = roi + (size_t)b * RR * 4;
    if (tid < RR) {
        const float4 r4 = reinterpret_cast<const float4*>(rb)[tid];
        sx[tid] = r4.x; sy[tid] = r4.y;
        sx1[tid] = __fadd_rn(r4.x, r4.z);
        sy1[tid] = __fadd_rn(r4.y, r4.w);
        sarea[tid] = __fmul_rn(r4.z, r4.w);
    }
    __syncthreads();

    // ---- ballot mask build, static 7-wave map (R9/R11 verbatim):
    // wave0: w0 t[0,64); waves1-2: w1 t[0,64),[64,128); waves3-6: w2 quarters of [0,159)
    {
        int w, tlo, thi;
        if (wid == 0)      { w = 0; tlo = 0;              thi = 64; }
        else if (wid <= 2) { w = 1; tlo = (wid - 1) * 64; thi = wid * 64; }
        else               { w = 2; int c = wid - 3; tlo = c * 159 / 4; thi = (c + 1) * 159 / 4; }

        const int j  = w * 64 + lane;
        const int jc = j < RR ? j : RR - 1;
        const float jx0 = sx[jc], jy0 = sy[jc], jx1 = sx1[jc], jy1 = sy1[jc], ja = sarea[jc];
        const bool jok = j < RR;

        #pragma unroll 4
        for (int t = tlo; t < thi; ++t) {
            const float xa = fmaxf(sx[t], jx0);
            const float ya = fmaxf(sy[t], jy0);
            const float xb = fminf(sx1[t], jx1);
            const float yb = fminf(sy1[t], jy1);
            const float iw  = fmaxf(__fsub_rn(xb, xa), 0.0f);
            const float ihh = fmaxf(__fsub_rn(yb, ya), 0.0f);
            const float inter = __fmul_rn(iw, ihh);
            const float denom = __fsub_rn(__fadd_rn(sarea[t], ja), inter);
            const bool pred = jok && (j > t) && (__fdiv_rn(inter, denom) > IOU_THRF);
            const unsigned long long bal = __ballot(pred);
            if (lane == 0) nsup[t][w] = ~bal;
        }
    }
    __syncthreads();

    // ---- scan + select + clip on wave 0 only (R11 verbatim) ----
    if (wid == 0) {
        unsigned long long k0 = ~0ull, k1 = ~0ull, k2 = (1ull << 32) - 1;
        #pragma unroll 8
        for (int t = 0; t < 64; ++t) {
            unsigned long long mb = ((k0 >> t) & 1ull) - 1ull;
            k0 &= nsup[t][0] | mb;
            k1 &= nsup[t][1] | mb;
            k2 &= nsup[t][2] | mb;
        }
        #pragma unroll 8
        for (int t = 64; t < 128; ++t) {
            unsigned long long mb = ((k1 >> (t - 64)) & 1ull) - 1ull;
            k1 &= nsup[t][1] | mb;
            k2 &= nsup[t][2] | mb;
        }
        #pragma unroll 8
        for (int t = 128; t < RR - 1; ++t) {
            unsigned long long mb = ((k2 >> (t - 128)) & 1ull) - 1ull;
            k2 &= nsup[t][2] | mb;
        }

        // select the n-th kept box (pad: box RR-1); n is block-uniform
        int src = RR - 1;
        int target = n;
        unsigned long long words[3] = {k0, k1, k2};
        #pragma unroll
        for (int w = 0; w < 3; ++w) {
            int pc = __popcll(words[w]);
            if (target < pc) {
                unsigned long long xw = words[w];
                for (int p = 0; p < target; ++p) xw &= xw - 1;
                src = w * 64 + (__ffsll((long long)xw) - 1);
                break;
            }
            target -= pc;
        }

        int bx0 = max(0, (int)sx[src]);
        int by0 = max(0, (int)sy[src]);
        int bx1 = min(WW, (int)sx1[src]);
        int by1 = min(HH, (int)sy1[src]);
        fix_span(bx0, bx1, PW, WW);
        fix_span(by0, by1, PH, HH);
        if (lane == 0) {
            sbox[0] = bx0; sbox[1] = by0; sbox[2] = bx1 - bx0; sbox[3] = by1 - by0;
        }
    }
    __syncthreads();

    // ---- pool (R5 verbatim): this block's pool-row i; wave = pool-col ----
    const int x0 = sbox[0], y0 = sbox[1], w = sbox[2], h = sbox[3];
    const int wave = wid;                // jj, 0..6 (wave-uniform)
    const int poff = lane >> 4;
    const int cq   = lane & 15;
    const int hs = h / PH, wsz = w / PW;

    const int r0 = y0 + i * hs;
    const int r1 = (i == PH - 1) ? (y0 + h) : (r0 + hs);
    const int c0 = x0 + wave * wsz;
    const int c1 = (wave == PW - 1) ? (x0 + w) : (c0 + wsz);

    const float* fb = feat + (size_t)b * HH * WW * CC;
    float4 v = make_float4(-INFINITY, -INFINITY, -INFINITY, -INFINITY);
    #pragma unroll 2
    for (int r = r0; r < r1; ++r) {
        const float* rowp = fb + (size_t)(r * WW) * CC;
        for (int base = c0; base < c1; base += 4) {
            int px = base + poff;
            px = px < c1 ? px : c1 - 1;
            const float4 t = *reinterpret_cast<const float4*>(rowp + (size_t)px * CC + cq * 4);
            v.x = fmaxf(v.x, t.x);
            v.y = fmaxf(v.y, t.y);
            v.z = fmaxf(v.z, t.z);
            v.w = fmaxf(v.w, t.w);
        }
    }
    // reduce over the 4 pixel-groups: lanes {cq, cq+16, cq+32, cq+48}
    v.x = fmaxf(v.x, __shfl_xor(v.x, 16));
    v.y = fmaxf(v.y, __shfl_xor(v.y, 16));
    v.z = fmaxf(v.z, __shfl_xor(v.z, 16));
    v.w = fmaxf(v.w, __shfl_xor(v.w, 16));
    v.x = fmaxf(v.x, __shfl_xor(v.x, 32));
    v.y = fmaxf(v.y, __shfl_xor(v.y, 32));
    v.z = fmaxf(v.z, __shfl_xor(v.z, 32));
    v.w = fmaxf(v.w, __shfl_xor(v.w, 32));

    if (poff == 0) {
        float4* o = reinterpret_cast<float4*>(
            out + ((((size_t)b * NREG + n) * PH + i) * PW + wave) * CC) + cq;
        *o = v;
    }
}

extern "C" void kernel_launch(void* const* d_in, const int* in_sizes, int n_in,
                              void* d_out, int out_size, void* d_ws, size_t ws_size,
                              hipStream_t stream) {
    const float* features = (const float*)d_in[0];
    const float* roi      = (const float*)d_in[1];
    float* out = (float*)d_out;

    fused_nosync<<<BB * NREG * PH, NTHR, 0, stream>>>(features, roi, out);
}

// Round 15
// 26.001 us; speedup vs baseline: 1.8628x; 1.8628x over previous
//
#include <hip/hip_runtime.h>

#define BB 4
#define RR 160
#define HH 128
#define WW 128
#define CC 64
#define NREG 32
#define PH 7
#define PW 7
#define IOU_THRF 0.4f

// floor division (Python // semantics) for possibly-negative numerators
__device__ __forceinline__ int fdiv(int a, int b) {
    int q = a / b, r = a % b;
    return (r != 0 && ((r < 0) != (b < 0))) ? q - 1 : q;
}

__device__ __forceinline__ void fix_span(int& lo, int& hi, int p, int s) {
    int pad = p - (hi - lo);
    bool fmin = lo < fdiv(pad, 2);
    bool fmax = (s - hi) < fdiv(1 + pad, 2);
    bool sym = (pad > 0) && !(fmin || fmax);
    int lo2 = sym ? lo - fdiv(pad, 2) : lo;
    int hi2 = sym ? hi + fdiv(1 + pad, 2) : hi;
    if ((pad > 0) && fmin) { lo2 = 0; hi2 = p; }
    if ((pad > 0) && fmax) { lo2 = s - p; hi2 = s; }
    lo = lo2; hi = hi2;
}

__device__ __forceinline__ float4 fmax4(float4 a, float4 b) {
    a.x = fmaxf(a.x, b.x); a.y = fmaxf(a.y, b.y);
    a.z = fmaxf(a.z, b.z); a.w = fmaxf(a.w, b.w);
    return a;
}

// R9 NMS kernel, verbatim (proven bit-exact; 1024 thr, 16-wave static map).
__global__ __launch_bounds__(1024)
void nms_clip_kernel(const float* __restrict__ roi, int* __restrict__ boxes_out) {
    const int b = blockIdx.x;
    const int tid = threadIdx.x;
    const int wid = tid >> 6;
    const int lane = tid & 63;

    __shared__ float sx[RR], sy[RR], sx1[RR], sy1[RR], sarea[RR];
    __shared__ unsigned long long nsup[RR][3];   // ~suppression words

    const float* rb = roi + (size_t)b * RR * 4;
    if (tid < RR) {
        const float4 r4 = reinterpret_cast<const float4*>(rb)[tid];
        sx[tid] = r4.x; sy[tid] = r4.y;
        sx1[tid] = __fadd_rn(r4.x, r4.z);
        sy1[tid] = __fadd_rn(r4.y, r4.w);
        sarea[tid] = __fmul_rn(r4.z, r4.w);
    }
    __syncthreads();

    {
        int w, tlo, thi;
        if (wid < 3)      { w = 0; tlo = wid * 64 / 3;              thi = (wid + 1) * 64 / 3; }
        else if (wid < 9) { w = 1; int c = wid - 3; tlo = c * 128 / 6; thi = (c + 1) * 128 / 6; }
        else              { w = 2; int c = wid - 9; tlo = c * 159 / 7; thi = (c + 1) * 159 / 7; }

        const int j  = w * 64 + lane;
        const int jc = j < RR ? j : RR - 1;
        const float jx0 = sx[jc], jy0 = sy[jc], jx1 = sx1[jc], jy1 = sy1[jc], ja = sarea[jc];
        const bool jok = j < RR;

        #pragma unroll 4
        for (int t = tlo; t < thi; ++t) {
            const float xa = fmaxf(sx[t], jx0);
            const float ya = fmaxf(sy[t], jy0);
            const float xb = fminf(sx1[t], jx1);
            const float yb = fminf(sy1[t], jy1);
            const float iw  = fmaxf(__fsub_rn(xb, xa), 0.0f);
            const float ihh = fmaxf(__fsub_rn(yb, ya), 0.0f);
            const float inter = __fmul_rn(iw, ihh);
            const float denom = __fsub_rn(__fadd_rn(sarea[t], ja), inter);
            const bool pred = jok && (j > t) && (__fdiv_rn(inter, denom) > IOU_THRF);
            const unsigned long long bal = __ballot(pred);
            if (lane == 0) nsup[t][w] = ~bal;
        }
    }
    __syncthreads();

    if (tid >= 64) return;

    unsigned long long k0 = ~0ull, k1 = ~0ull, k2 = (1ull << 32) - 1;
    #pragma unroll 8
    for (int t = 0; t < 64; ++t) {
        unsigned long long mb = ((k0 >> t) & 1ull) - 1ull;
        k0 &= nsup[t][0] | mb;
        k1 &= nsup[t][1] | mb;
        k2 &= nsup[t][2] | mb;
    }
    #pragma unroll 8
    for (int t = 64; t < 128; ++t) {
        unsigned long long mb = ((k1 >> (t - 64)) & 1ull) - 1ull;
        k1 &= nsup[t][1] | mb;
        k2 &= nsup[t][2] | mb;
    }
    #pragma unroll 8
    for (int t = 128; t < RR - 1; ++t) {
        unsigned long long mb = ((k2 >> (t - 128)) & 1ull) - 1ull;
        k2 &= nsup[t][2] | mb;
    }

    if (tid >= NREG) return;

    int src = RR - 1;
    {
        int target = tid;
        unsigned long long words[3] = {k0, k1, k2};
        #pragma unroll
        for (int w = 0; w < 3; ++w) {
            int pc = __popcll(words[w]);
            if (target < pc) {
                unsigned long long x = words[w];
                for (int q = 0; q < target; ++q) x &= x - 1;
                src = w * 64 + (__ffsll((long long)x) - 1);
                break;
            }
            target -= pc;
        }
    }

    int x0 = max(0, (int)sx[src]);
    int y0 = max(0, (int)sy[src]);
    int x1 = min(WW, (int)sx1[src]);
    int y1 = min(HH, (int)sy1[src]);
    fix_span(x0, x1, PW, WW);
    fix_span(y0, y1, PH, HH);
    int* o = boxes_out + ((size_t)b * NREG + tid) * 4;
    o[0] = x0; o[1] = y0; o[2] = x1 - x0; o[3] = y1 - y0;
}

// Pool v2: break the load->fmax serial chain. Per wave (one 7x7 cell):
// outer loop over <=3 column-groups (px clamped once), inner loop over rows
// in CHUNKS OF 4 with 4 independent temps + 4 independent accumulators
// (all statically indexed). Each chunk issues 4 independent dwordx4 loads
// back-to-back -> one latency stall per 4 loads instead of per load.
// Row-clamp duplicates (<=3/chunk, same cachelines) are harmless for max.
__global__ __launch_bounds__(PW * CC)
void pool_kernel(const float* __restrict__ feat, const int* __restrict__ boxes,
                 float* __restrict__ out) {
    // bijective XCD decode: xcd x = g%8 owns (b,n) pairs [x*16, x*16+16)
    const int g = blockIdx.x;
    const int x = g & 7;
    const int q = g >> 3;
    const int pair = x * 16 + q / 7;
    const int i = q % 7;
    const int n = pair & (NREG - 1);
    const int b = pair >> 5;

    const int wave = threadIdx.x >> 6;   // jj, 0..6 (wave-uniform)
    const int lane = threadIdx.x & 63;
    const int poff = lane >> 4;          // 0..3 pixel offset within group
    const int cq   = lane & 15;          // 0..15 channel quad

    const int4 bx = *reinterpret_cast<const int4*>(boxes + ((size_t)b * NREG + n) * 4);
    const int x0 = bx.x, y0 = bx.y, w = bx.z, h = bx.w;
    const int hs = h / PH, wsz = w / PW;

    const int r0 = y0 + i * hs;
    const int r1 = (i == PH - 1) ? (y0 + h) : (r0 + hs);
    const int c0 = x0 + wave * wsz;
    const int c1 = (wave == PW - 1) ? (x0 + w) : (c0 + wsz);
    const int nr = r1 - r0;              // 1..~10
    const int ng = (c1 - c0 + 3) >> 2;   // 1..3 column groups

    const float* fb = feat + (size_t)b * HH * WW * CC + (size_t)cq * 4;

    const float4 NEG = make_float4(-INFINITY, -INFINITY, -INFINITY, -INFINITY);
    float4 a0 = NEG, a1 = NEG, a2 = NEG, a3 = NEG;

    for (int gg = 0; gg < ng; ++gg) {
        int px = c0 + (gg << 2) + poff;
        px = px < c1 ? px : c1 - 1;
        const float* colp = fb + (size_t)px * CC;
        for (int rr = 0; rr < nr; rr += 4) {
            const int q1 = min(rr + 1, nr - 1);
            const int q2 = min(rr + 2, nr - 1);
            const int q3 = min(rr + 3, nr - 1);
            const float4 t0 = *reinterpret_cast<const float4*>(colp + (size_t)(r0 + rr) * (WW * CC));
            const float4 t1 = *reinterpret_cast<const float4*>(colp + (size_t)(r0 + q1) * (WW * CC));
            const float4 t2 = *reinterpret_cast<const float4*>(colp + (size_t)(r0 + q2) * (WW * CC));
            const float4 t3 = *reinterpret_cast<const float4*>(colp + (size_t)(r0 + q3) * (WW * CC));
            a0 = fmax4(a0, t0);
            a1 = fmax4(a1, t1);
            a2 = fmax4(a2, t2);
            a3 = fmax4(a3, t3);
        }
    }
    float4 v = fmax4(fmax4(a0, a1), fmax4(a2, a3));

    // reduce over the 4 pixel-groups: lanes {cq, cq+16, cq+32, cq+48}
    v.x = fmaxf(v.x, __shfl_xor(v.x, 16));
    v.y = fmaxf(v.y, __shfl_xor(v.y, 16));
    v.z = fmaxf(v.z, __shfl_xor(v.z, 16));
    v.w = fmaxf(v.w, __shfl_xor(v.w, 16));
    v.x = fmaxf(v.x, __shfl_xor(v.x, 32));
    v.y = fmaxf(v.y, __shfl_xor(v.y, 32));
    v.z = fmaxf(v.z, __shfl_xor(v.z, 32));
    v.w = fmaxf(v.w, __shfl_xor(v.w, 32));

    if (poff == 0) {
        float4* o = reinterpret_cast<float4*>(
            out + ((((size_t)b * NREG + n) * PH + i) * PW + wave) * CC) + cq;
        *o = v;
    }
}

extern "C" void kernel_launch(void* const* d_in, const int* in_sizes, int n_in,
                              void* d_out, int out_size, void* d_ws, size_t ws_size,
                              hipStream_t stream) {
    const float* features = (const float*)d_in[0];
    const float* roi      = (const float*)d_in[1];
    float* out = (float*)d_out;
    int* boxes = (int*)d_ws;   // BB*NREG*4 ints = 2 KB

    nms_clip_kernel<<<BB, 1024, 0, stream>>>(roi, boxes);
    pool_kernel<<<BB * NREG * PH, PW * CC, 0, stream>>>(features, boxes, out);
}